// Round 7
// baseline (1501.085 us; speedup 1.0000x reference)
//
#include <hip/hip_runtime.h>
#include <math.h>

// Problem constants
#define BB 8
#define NN 4096
#define CC 96
#define C2 192
#define NP 1024
#define NS 16
#define PPT 16   // points per thread in FPS (256 threads * 16 = 4096)

// ws layout (bytes)
#define SAMP_OFF   0u           // int[8*1024]            32768
#define NBR_OFF    32768u       // int[8*1024*16]        524288
#define WSW_OFF    655360u      // (unused)
#define B1_OFF     802816u      // float[192]               768
#define WCT_OFF    803584u      // float[192*192]        147456
#define B2_OFF     951040u      // float[192]               768
#define ZT_OFF     958464u      // float[8*4096*384]   50331648

#define GEMM_OFF   152          // first gemm block in launch 1 (8 fps + 144 prep)

// f32 DPP max step: combines shifted neighbor via fmaxf (old=0 identity is
// safe: distances are nonneg). Sequence validated on HW (r5/r6 bit-exact).
template<int CTRL, int RM>
__device__ __forceinline__ float dpp_maxf(float v) {
    int t = __builtin_amdgcn_update_dpp(0, __float_as_int(v), CTRL, RM, 0xf, false);
    return fmaxf(v, __int_as_float(t));
}

// ---------------------------------------------------------------------------
// Launch 1: blocks 0..7 = FPS; 8..151 = prep (beta/WcT); 152..3223 = GEMM1.
// FPS: 256 threads (4 waves, 1/SIMD), 16 pts/thread in registers.
// Exact reference arithmetic: ((dx*dx+dy*dy)+dz*dz) via _rn intrinsics.
// Wave argmax: f32 DPP max-reduce + ballot first-lane (lane order == index
// order); cross-wave: 4 exact u64 keys + coords in one LDS round.
// GEMM1 self-folds BN scales (needs only inputs) -> overlaps FPS.
// ---------------------------------------------------------------------------
__global__ __launch_bounds__(256) void fps_prep_gemm_kernel(
        const float* __restrict__ p, const float* __restrict__ x,
        const float* __restrict__ Wt, const float* __restrict__ gt,
        const float* __restrict__ bt, const float* __restrict__ mt,
        const float* __restrict__ vt, const float* __restrict__ Wc,
        const float* __restrict__ gc, const float* __restrict__ bc,
        const float* __restrict__ mc, const float* __restrict__ vc,
        float* __restrict__ beta1, float* __restrict__ WcT,
        float* __restrict__ beta2, float* __restrict__ zt,
        int* __restrict__ samp, float* __restrict__ out) {
    int tid = threadIdx.x;

    if (blockIdx.x >= GEMM_OFF) {
        // ---- GEMM1: zt[b][j][384] = (Wt*s1)[384x96] @ relu(x[b][:, j]) ----
        __shared__ float smem[12416];
        float* xt = smem;            // [96][64]
        float* wt = smem + 6144;     // [64][97]
        float* s1s = smem + 12352;   // [64]
        int g = blockIdx.x - GEMM_OFF;
        int b = g & 7;
        int t2 = g >> 3;             // 0..383
        int ob = t2 >> 6;            // 0..5
        int jt = t2 & 63;            // 0..63

        if (tid < 64) {
            int grow = ob * 64 + tid;
            int o = (grow < C2) ? grow : grow - C2;
            s1s[tid] = gt[o] / sqrtf(vt[o] + 1e-5f);
        }
        for (int idx = tid; idx < 96 * 64; idx += 256) {
            int c = idx >> 6, j = idx & 63;
            xt[c * 64 + j] = fmaxf(x[((size_t)b * CC + c) * NN + jt * 64 + j], 0.0f);
        }
        __syncthreads();
        for (int idx = tid; idx < 64 * 96; idx += 256) {
            int r = idx / 96, c = idx - r * 96;
            int grow = ob * 64 + r;
            float w = (grow < C2) ? Wt[grow * C2 + c] : Wt[(grow - C2) * C2 + 96 + c];
            wt[r * 97 + c] = w * s1s[r];
        }
        __syncthreads();

        int ty = tid >> 4, tx = tid & 15;
        float acc[4][4] = {};
        for (int k = 0; k < 96; ++k) {
            float a0 = wt[(ty * 4 + 0) * 97 + k];
            float a1 = wt[(ty * 4 + 1) * 97 + k];
            float a2 = wt[(ty * 4 + 2) * 97 + k];
            float a3 = wt[(ty * 4 + 3) * 97 + k];
            float4 bv = *(const float4*)&xt[k * 64 + tx * 4];
            acc[0][0] = fmaf(a0, bv.x, acc[0][0]); acc[0][1] = fmaf(a0, bv.y, acc[0][1]);
            acc[0][2] = fmaf(a0, bv.z, acc[0][2]); acc[0][3] = fmaf(a0, bv.w, acc[0][3]);
            acc[1][0] = fmaf(a1, bv.x, acc[1][0]); acc[1][1] = fmaf(a1, bv.y, acc[1][1]);
            acc[1][2] = fmaf(a1, bv.z, acc[1][2]); acc[1][3] = fmaf(a1, bv.w, acc[1][3]);
            acc[2][0] = fmaf(a2, bv.x, acc[2][0]); acc[2][1] = fmaf(a2, bv.y, acc[2][1]);
            acc[2][2] = fmaf(a2, bv.z, acc[2][2]); acc[2][3] = fmaf(a2, bv.w, acc[2][3]);
            acc[3][0] = fmaf(a3, bv.x, acc[3][0]); acc[3][1] = fmaf(a3, bv.y, acc[3][1]);
            acc[3][2] = fmaf(a3, bv.z, acc[3][2]); acc[3][3] = fmaf(a3, bv.w, acc[3][3]);
        }
        for (int jj = 0; jj < 4; ++jj) {
            int j = jt * 64 + tx * 4 + jj;
            float4 v = make_float4(acc[0][jj], acc[1][jj], acc[2][jj], acc[3][jj]);
            *(float4*)&zt[((size_t)b * NN + j) * 384 + ob * 64 + ty * 4] = v;
        }
        return;
    }

    if (blockIdx.x >= BB) {
        // ---- prep: beta1/beta2 + WcT (Wc*s2 transposed) ----
        int i = (blockIdx.x - BB) * 256 + tid;
        if (i < C2) {
            float s1 = gt[i] / sqrtf(vt[i] + 1e-5f);
            beta1[i] = bt[i] - mt[i] * s1;
            float s2 = gc[i] / sqrtf(vc[i] + 1e-5f);
            beta2[i] = bc[i] - mc[i] * s2;
        }
        if (i < C2 * C2) {
            int o = i / C2, c = i - o * C2;
            float s2 = gc[o] / sqrtf(vc[o] + 1e-5f);
            WcT[c * C2 + o] = Wc[i] * s2;
        }
        return;
    }

    // ---- FPS ----
    {
    int b = blockIdx.x;
    const float* pb = p + (size_t)b * NN * 3;
    __shared__ unsigned long long redk[2][4];
    __shared__ float4 redc[2][4];
    int jbase = tid * PPT;

    // load 48 contiguous floats (16 points) per thread into registers
    float c48[48];
    const float4* pb4 = (const float4*)(pb + (size_t)jbase * 3);
    #pragma unroll
    for (int i = 0; i < 12; ++i) ((float4*)c48)[i] = pb4[i];
    float px[PPT], py[PPT], pz[PPT], mind[PPT];
    #pragma unroll
    for (int i = 0; i < PPT; ++i) {
        px[i] = c48[3*i+0]; py[i] = c48[3*i+1]; pz[i] = c48[3*i+2];
        mind[i] = 1e10f;
    }

    int last = 0;
    float lx = pb[0], ly = pb[1], lz = pb[2];

    for (int it = 0; it < NP; ++it) {
        if (tid == 0) {
            samp[b * NP + it] = last;
            size_t o3 = ((size_t)b * NP + it) * 3;
            out[o3 + 0] = lx; out[o3 + 1] = ly; out[o3 + 2] = lz;
        }
        // exact-scan distance update
        float m[PPT];
        #pragma unroll
        for (int i = 0; i < PPT; ++i) {
            float dx = __fsub_rn(px[i], lx);
            float dy = __fsub_rn(py[i], ly);
            float dz = __fsub_rn(pz[i], lz);
            float d = __fadd_rn(__fadd_rn(__fmul_rn(dx, dx), __fmul_rn(dy, dy)),
                                __fmul_rn(dz, dz));
            float mi = fminf(mind[i], d);
            mind[i] = mi;
            m[i] = mi;
        }
        // tournament argmax over 16 (strict > keeps lower index on ties)
        float v8[8]; int i8v[8];
        #pragma unroll
        for (int q = 0; q < 8; ++q) {
            bool t = m[2*q+1] > m[2*q];
            v8[q] = t ? m[2*q+1] : m[2*q];
            i8v[q] = t ? 2*q+1 : 2*q;
        }
        float v4[4]; int i4v[4];
        #pragma unroll
        for (int q = 0; q < 4; ++q) {
            bool t = v8[2*q+1] > v8[2*q];
            v4[q] = t ? v8[2*q+1] : v8[2*q];
            i4v[q] = t ? i8v[2*q+1] : i8v[2*q];
        }
        float v2a[2]; int i2v[2];
        #pragma unroll
        for (int q = 0; q < 2; ++q) {
            bool t = v4[2*q+1] > v4[2*q];
            v2a[q] = t ? v4[2*q+1] : v4[2*q];
            i2v[q] = t ? i4v[2*q+1] : i4v[2*q];
        }
        bool tf = v2a[1] > v2a[0];
        float bv = tf ? v2a[1] : v2a[0];
        int ii  = tf ? i2v[1] : i2v[0];

        // wave64 f32 max-reduce via DPP; full max lands in lane 63
        float r = bv;
        r = dpp_maxf<0x111, 0xf>(r);   // row_shr:1
        r = dpp_maxf<0x112, 0xf>(r);   // row_shr:2
        r = dpp_maxf<0x114, 0xf>(r);   // row_shr:4
        r = dpp_maxf<0x118, 0xf>(r);   // row_shr:8
        r = dpp_maxf<0x142, 0xa>(r);   // row_bcast:15
        r = dpp_maxf<0x143, 0xc>(r);   // row_bcast:31
        float wmax = __int_as_float(__builtin_amdgcn_readlane(__float_as_int(r), 63));

        // first lane holding wmax == lowest point index (lane order == index
        // order within a wave; within-thread ii already lowest)
        unsigned long long ball = __ballot(bv == wmax);
        int winlane = (int)(__ffsll((long long)ball) - 1);
        int buf = it & 1;
        if ((tid & 63) == winlane) {
            int wv = tid >> 6;
            redk[buf][wv] = ((unsigned long long)__float_as_uint(bv) << 32)
                            | (unsigned long long)(unsigned)(4095 - (jbase + ii));
            redc[buf][wv] = make_float4(px[ii], py[ii], pz[ii], 0.0f);
        }
        __syncthreads();

        // single uniform LDS round: 4 (key,coord) tuples, exact u64 merge
        unsigned long long k0 = redk[buf][0], k1 = redk[buf][1];
        unsigned long long k2 = redk[buf][2], k3 = redk[buf][3];
        float4 c0 = redc[buf][0], c1 = redc[buf][1];
        float4 c2 = redc[buf][2], c3 = redc[buf][3];
        #define MRG(ka, ca, kb, cb) { bool tm = (kb) > (ka); \
            ka = tm ? (kb) : (ka); \
            ca.x = tm ? cb.x : ca.x; ca.y = tm ? cb.y : ca.y; ca.z = tm ? cb.z : ca.z; }
        MRG(k0, c0, k1, c1); MRG(k2, c2, k3, c3); MRG(k0, c0, k2, c2);
        #undef MRG
        last = 4095 - (int)(unsigned)(k0 & 0xffffffffull);
        lx = c0.x; ly = c0.y; lz = c0.z;
        // redk/redc double-buffered: next write to this buf is 2 barriers away
    }
    }
}

// ---------------------------------------------------------------------------
// Launch 2: ball query only (gemm moved to launch 1). One wave per center.
// ---------------------------------------------------------------------------
__global__ __launch_bounds__(256) void ballquery_kernel(
        const float* __restrict__ p, const float* __restrict__ newp,
        int* __restrict__ nbr) {
    __shared__ float sx[NN], sy[NN], sz[NN];
    int blk = blockIdx.x;              // 2048 blocks, 256 per batch
    int b = blk >> 8;
    int tid = threadIdx.x;
    const float* pb = p + (size_t)b * NN * 3;
    for (int idx = tid; idx < NN; idx += 256) {
        sx[idx] = pb[idx * 3 + 0];
        sy[idx] = pb[idx * 3 + 1];
        sz[idx] = pb[idx * 3 + 2];
    }
    __syncthreads();
    int wave = tid >> 6, lane = tid & 63;
    int g = (blk & 255) * 4 + wave;    // 0..1023
    int gidx = b * NP + g;
    float cx = newp[(size_t)gidx * 3 + 0];
    float cy = newp[(size_t)gidx * 3 + 1];
    float cz = newp[(size_t)gidx * 3 + 2];
    const float R2 = 0.01f;
    int cnt = 0, first = -1;
    for (int chunk = 0; chunk < NN / 64 && cnt < NS; ++chunk) {
        int j = chunk * 64 + lane;
        float dx = __fsub_rn(cx, sx[j]);
        float dy = __fsub_rn(cy, sy[j]);
        float dz = __fsub_rn(cz, sz[j]);
        float d2 = __fadd_rn(__fadd_rn(__fmul_rn(dx, dx), __fmul_rn(dy, dy)),
                             __fmul_rn(dz, dz));
        unsigned long long mask = __ballot(d2 < R2);
        while (mask && cnt < NS) {
            int bit = __ffsll(mask) - 1;
            mask &= mask - 1;
            int idx = chunk * 64 + bit;
            if (first < 0) first = idx;
            if (lane == 0) nbr[(size_t)gidx * NS + cnt] = idx;
            ++cnt;
        }
    }
    if (lane == 0) {
        for (int i = cnt; i < NS; ++i) nbr[(size_t)gidx * NS + i] = first;
    }
}

// ---------------------------------------------------------------------------
// Fused: gather zc+zn, +beta -> relu, sin/cos pos embed, agg=(t+1)*emb,
// max+mean pool, relu, 192x192 conv2 (BN folded) -> relu -> f32 store.
// ---------------------------------------------------------------------------
__global__ __launch_bounds__(192) void fused_kernel(const float* __restrict__ p,
                                                    const float* __restrict__ newp,
                                                    const int* __restrict__ samp,
                                                    const int* __restrict__ nbr,
                                                    const float* __restrict__ zt,
                                                    const float* __restrict__ beta1,
                                                    const float* __restrict__ WcT,
                                                    const float* __restrict__ beta2,
                                                    float* __restrict__ out) {
    int blk = blockIdx.x;
    int b = blk >> 10, g = blk & 1023;
    int tid = threadIdx.x;
    __shared__ float dp[3][NS];
    __shared__ int nb[NS];
    __shared__ float pl[C2];

    if (tid < NS) {
        int j = nbr[(size_t)blk * NS + tid];
        nb[tid] = j;
        dp[0][tid] = p[((size_t)b * NN + j) * 3 + 0] - newp[(size_t)blk * 3 + 0];
        dp[1][tid] = p[((size_t)b * NN + j) * 3 + 1] - newp[(size_t)blk * 3 + 1];
        dp[2][tid] = p[((size_t)b * NN + j) * 3 + 2] - newp[(size_t)blk * 3 + 2];
    }
    __syncthreads();

    int o = tid;
    int sidx = samp[blk];
    float zc = zt[((size_t)b * NN + sidx) * 384 + o];
    float bet = beta1[o];
    int axis = o >> 6;        // 0..2
    int k = o & 63;
    int kk = (k < 32) ? k : k - 32;
    float dim = powf(500.0f, (float)kk * (1.0f / 32.0f));

    float mx = -3.4e38f, sm = 0.0f;
    for (int s = 0; s < NS; ++s) {
        float zn = zt[((size_t)b * NN + nb[s]) * 384 + C2 + o];
        float t = fmaxf(zc + zn + bet, 0.0f);
        float pos = (50.0f * dp[axis][s]) / dim;
        float e = (k < 32) ? sinf(pos) : cosf(pos);
        float a = fmaf(t, e, e);          // xj*emb + emb
        mx = fmaxf(mx, a);
        sm += a;
    }
    pl[o] = fmaxf(mx + sm * (1.0f / 16.0f), 0.0f);
    __syncthreads();

    float acc = 0.0f;
    for (int c = 0; c < C2; ++c) acc = fmaf(WcT[c * C2 + o], pl[c], acc);
    float res = fmaxf(acc + beta2[o], 0.0f);
    out[BB * NP * 3 + ((size_t)b * C2 + o) * NP + g] = res;
}

// ---------------------------------------------------------------------------
extern "C" void kernel_launch(void* const* d_in, const int* in_sizes, int n_in,
                              void* d_out, int out_size, void* d_ws, size_t ws_size,
                              hipStream_t stream) {
    (void)in_sizes; (void)n_in; (void)out_size; (void)ws_size;
    const float* p  = (const float*)d_in[0];
    const float* x  = (const float*)d_in[1];
    const float* Wt = (const float*)d_in[2];
    const float* gt = (const float*)d_in[3];
    const float* bt = (const float*)d_in[4];
    const float* mt = (const float*)d_in[5];
    const float* vt = (const float*)d_in[6];
    const float* Wc = (const float*)d_in[7];
    const float* gc = (const float*)d_in[8];
    const float* bc = (const float*)d_in[9];
    const float* mc = (const float*)d_in[10];
    const float* vc = (const float*)d_in[11];
    float* out = (float*)d_out;              // f32 output (reference is all-f32)
    char* ws = (char*)d_ws;

    int*   samp  = (int*)(ws + SAMP_OFF);
    int*   nbr   = (int*)(ws + NBR_OFF);
    float* beta1 = (float*)(ws + B1_OFF);
    float* WcT   = (float*)(ws + WCT_OFF);
    float* beta2 = (float*)(ws + B2_OFF);
    float* zt    = (float*)(ws + ZT_OFF);
    const float* newp = out;                 // new_p lives in d_out[0 .. 24576)

    fps_prep_gemm_kernel<<<dim3(GEMM_OFF + 3072), dim3(256), 0, stream>>>(
        p, x, Wt, gt, bt, mt, vt, Wc, gc, bc, mc, vc,
        beta1, WcT, beta2, zt, samp, out);
    ballquery_kernel<<<dim3(2048), dim3(256), 0, stream>>>(p, newp, nbr);
    fused_kernel<<<dim3(BB * NP), dim3(192), 0, stream>>>(
        p, newp, samp, nbr, zt, beta1, WcT, beta2, out);
}